// Round 17
// baseline (128.165 us; speedup 1.0000x reference)
//
#include <hip/hip_runtime.h>
#include <hip/hip_bf16.h>
#include <cstdint>

typedef unsigned short u16;
typedef __bf16 bf16_t;
typedef __bf16 bf16x8 __attribute__((ext_vector_type(8)));
typedef float f32x4 __attribute__((ext_vector_type(4)));

#define DM   512
#define DFF  2048
#define NEXP 8

__device__ __forceinline__ u16 f2bf(float f) {
  bf16_t b = (bf16_t)f;
  return __builtin_bit_cast(u16, b);
}
__device__ __forceinline__ uint32_t pack_bf2(float lo, float hi) {
  return (uint32_t)f2bf(lo) | ((uint32_t)f2bf(hi) << 16);
}
__device__ __forceinline__ float gelu_tanh(float x) {
  float x3 = x * x * x;
  float z = 0.7978845608028654f * (x + 0.044715f * x3);
  float az = fabsf(z);
  float e = __expf(2.0f * az);
  float t = 1.0f - 2.0f / (e + 1.0f);
  t = copysignf(t, z);
  return 0.5f * x * (1.0f + t);
}
__device__ __forceinline__ void async16(const u16* g, u16* l) {
  __builtin_amdgcn_global_load_lds((const __attribute__((address_space(1))) void*)g,
                                   (__attribute__((address_space(3))) void*)l, 16, 0, 0);
}

// ---------- transpose tile body: src [R][C] f32 -> dst [C][R] bf16 (16B stores)
__device__ __forceinline__ void transpose_tile(const float* __restrict__ s,
                                               u16* __restrict__ d, int R, int C,
                                               int tileIdx) {
  __shared__ u16 tile[64][66];
  int tilesC = C >> 6;
  int bR = (tileIdx / tilesC) << 6;
  int bC = (tileIdx % tilesC) << 6;
  int rr = threadIdx.x >> 4;
  int cc = (threadIdx.x & 15) << 2;
#pragma unroll
  for (int i = 0; i < 4; ++i) {
    int r = (i << 4) + rr;
    float4 v = *(const float4*)(s + (size_t)(bR + r) * C + bC + cc);
    *(uint32_t*)&tile[r][cc]     = pack_bf2(v.x, v.y);
    *(uint32_t*)&tile[r][cc + 2] = pack_bf2(v.z, v.w);
  }
  __syncthreads();
  int c  = threadIdx.x >> 3;          // 0..31
  int j0 = (threadIdx.x & 7) << 3;    // 0,8,...,56
#pragma unroll
  for (int half = 0; half < 2; ++half) {
    int cc2 = c + (half << 5);
    uint32_t w0 = (uint32_t)tile[j0 + 0][cc2] | ((uint32_t)tile[j0 + 1][cc2] << 16);
    uint32_t w1 = (uint32_t)tile[j0 + 2][cc2] | ((uint32_t)tile[j0 + 3][cc2] << 16);
    uint32_t w2 = (uint32_t)tile[j0 + 4][cc2] | ((uint32_t)tile[j0 + 5][cc2] << 16);
    uint32_t w3 = (uint32_t)tile[j0 + 6][cc2] | ((uint32_t)tile[j0 + 7][cc2] << 16);
    *(uint4*)(&d[(size_t)(bC + cc2) * R + bR + j0]) = make_uint4(w0, w1, w2, w3);
  }
}

// ---------- fused prep: W1 transpose | W2 transpose | router (+x->bf16 folded in)
__global__ void k_prep(const float* __restrict__ W1, u16* __restrict__ W1T,
                       const float* __restrict__ W2, u16* __restrict__ W2T,
                       const float* __restrict__ x, u16* __restrict__ Xb,
                       const float* __restrict__ Wr, const float* __restrict__ br,
                       int* __restrict__ sel_idx, float* __restrict__ sel_w, int Ntok) {
  int b = blockIdx.x;
  if (b < 2048) {
    int e = b >> 8, t = b & 255;
    transpose_tile(W1 + (size_t)e * DM * DFF, W1T + (size_t)e * DM * DFF, DM, DFF, t);
    return;
  }
  if (b < 4096) {
    int e = (b - 2048) >> 8, t = (b - 2048) & 255;
    transpose_tile(W2 + (size_t)e * DFF * DM, W2T + (size_t)e * DFF * DM, DFF, DM, t);
    return;
  }
  int rb = b - 4096;
  int wid = threadIdx.x >> 6;
  int lane = threadIdx.x & 63;
  int tok = (rb << 2) + wid;
  if (tok >= Ntok) return;
  const float4* xr = (const float4*)(x + (size_t)tok * DM);
  float4 x0 = xr[lane * 2], x1 = xr[lane * 2 + 1];
  // fold x->bf16 into router: row already in registers, 16B/lane store
  {
    uint4 o;
    o.x = pack_bf2(x0.x, x0.y);
    o.y = pack_bf2(x0.z, x0.w);
    o.z = pack_bf2(x1.x, x1.y);
    o.w = pack_bf2(x1.z, x1.w);
    ((uint4*)(Xb + (size_t)tok * DM))[lane] = o;
  }
  float logit[NEXP];
#pragma unroll
  for (int e = 0; e < NEXP; ++e) {
    const float4* wr = (const float4*)(Wr + e * DM);
    float4 w0 = wr[lane * 2], w1 = wr[lane * 2 + 1];
    float p = x0.x * w0.x + x0.y * w0.y + x0.z * w0.z + x0.w * w0.w
            + x1.x * w1.x + x1.y * w1.y + x1.z * w1.z + x1.w * w1.w;
#pragma unroll
    for (int off = 32; off; off >>= 1) p += __shfl_xor(p, off, 64);
    logit[e] = p + br[e];
  }
  if (lane == 0) {
    float mx = logit[0];
#pragma unroll
    for (int e = 1; e < NEXP; ++e) mx = fmaxf(mx, logit[e]);
    float pr[NEXP];
#pragma unroll
    for (int e = 0; e < NEXP; ++e) pr[e] = __expf(logit[e] - mx);
    int i0 = 0;
#pragma unroll
    for (int e = 1; e < NEXP; ++e) if (pr[e] > pr[i0]) i0 = e;
    int i1 = -1;
#pragma unroll
    for (int e = 0; e < NEXP; ++e) {
      if (e == i0) continue;
      if (i1 < 0 || pr[e] > pr[i1]) i1 = e;
    }
    float s2 = pr[i0] + pr[i1];
    sel_idx[tok * 2]     = i0;
    sel_idx[tok * 2 + 1] = i1;
    sel_w[tok * 2]       = pr[i0] / s2;
    sel_w[tok * 2 + 1]   = pr[i1] / s2;
  }
}

// ---------- scatter: 8 blocks, one expert each; block 0 also writes tileMeta.
__global__ void k_scatter(const int* __restrict__ sel_idx, const float* __restrict__ sel_w,
                          int npairs, int* __restrict__ row_token, float* __restrict__ row_w,
                          int* __restrict__ pos_of, int* __restrict__ tileMeta,
                          int* __restrict__ gMeta) {
  __shared__ int cnt[NEXP], offs[NEXP], cur;
  int eb = blockIdx.x;
  int tid = threadIdx.x;
  int lane = tid & 63;
  if (tid < NEXP) cnt[tid] = 0;
  if (tid == 0) cur = 0;
  __syncthreads();
  for (int p = tid; p < npairs; p += blockDim.x) {
    int e = sel_idx[p];
#pragma unroll
    for (int ex = 0; ex < NEXP; ++ex) {
      unsigned long long m = __ballot(e == ex);
      if (lane == 0 && m) atomicAdd(&cnt[ex], __popcll(m));
    }
  }
  __syncthreads();
  if (tid == 0) {
    int o = 0;
    for (int e = 0; e < NEXP; ++e) { offs[e] = o; o += cnt[e]; }
    if (eb == 0) {
      int nmt = 0;
      for (int e = 0; e < NEXP; ++e) {
        int c = cnt[e];
        int nt = (c + 127) >> 7;
        for (int t = 0; t < nt; ++t) {
          tileMeta[nmt * 3 + 0] = offs[e] + t * 128;
          tileMeta[nmt * 3 + 1] = offs[e] + c;
          tileMeta[nmt * 3 + 2] = e;
          ++nmt;
        }
      }
      gMeta[0] = nmt;
    }
  }
  __syncthreads();
  for (int p = tid; p < npairs; p += blockDim.x) {
    int e = sel_idx[p];
    unsigned long long m = __ballot(e == eb);
    if (m) {
      int leader = __ffsll((long long)m) - 1;
      int base = 0;
      if (lane == leader) base = atomicAdd(&cur, __popcll(m));
      base = __shfl(base, leader, 64);
      if (e == eb) {
        int pos = offs[eb] + base + __popcll(m & ((1ull << lane) - 1ull));
        row_token[pos] = p >> 1;
        row_w[pos] = sel_w[p];
        pos_of[p] = pos;
      }
    }
  }
}

// ---------- grouped GEMM (R3-proven pipeline), BM=128 x BN (64 or 128), BK=32,
// 3-slot ring, counted vmcnt (one stage in flight), 1 barrier/K-tile,
// 256 thr / 4 waves (2x2). BN=64: slot 12KB -> 36KB LDS -> 4 blocks/CU.
template <int BN, int NFULL, int KTOT, int KCHUNK, int NSPLIT, bool GELU, bool SCALE,
          bool OUTBF16, bool USEMAP>
__launch_bounds__(256)
__global__ void k_gemm(const u16* __restrict__ A, const int* __restrict__ rowMap,
                       const u16* __restrict__ BT,
                       const float* __restrict__ bias, const float* __restrict__ row_w,
                       void* __restrict__ Out, size_t pstride,
                       const int* __restrict__ tileMeta, const int* __restrict__ gMeta,
                       int maxmt) {
  constexpr int NT  = NFULL / BN;
  constexpr int NK  = KCHUNK / 32;
  constexpr int NI  = BN / 32;              // bv frags per wave (wave covers BN/2 cols)
  constexpr int NBI = BN / 64;              // B staging instrs per tile
  constexpr int SLOTU = (128 + BN) * 32;    // u16 per slot (A 4096 + B BN*32)
  constexpr int LPS = 2 + NBI;              // loads per stage

  __shared__ __align__(16) u16 smem[3 * SLOTU];

  int NB = gridDim.x;
  int bid = blockIdx.x;
  int wg = ((NB & 7) == 0) ? ((bid & 7) * (NB >> 3) + (bid >> 3)) : bid;  // XCD chunking
  int nt = wg % NT;
  int rem = wg / NT;
  int mt = rem % maxmt;
  int split = (NSPLIT == 1) ? 0 : rem / maxmt;
  if (mt >= gMeta[0]) return;
  int posStart = tileMeta[mt * 3 + 0];
  int segEnd   = tileMeta[mt * 3 + 1];
  int e        = tileMeta[mt * 3 + 2];

  int tid = threadIdx.x, lane = tid & 63, wid = tid >> 6;
  int wm = wid >> 1, wn = wid & 1;

  const u16* Abase = A + (size_t)split * KCHUNK;
  const u16* Bbase = BT + ((size_t)e * NFULL + (size_t)nt * BN) * KTOT + (size_t)split * KCHUNK;

  int l4 = lane >> 2, c4 = lane & 3;
  const u16* aS[2];
  const u16* bS[NBI];
#pragma unroll
  for (int i = 0; i < 2; ++i) {
    int r = i * 64 + wid * 16 + l4;
    int gra = posStart + r;
    if (gra >= segEnd) gra = segEnd - 1;
    if constexpr (USEMAP) gra = rowMap[gra];
    int cs = c4 ^ ((r >> 1) & 3);
    aS[i] = Abase + (size_t)gra * KTOT + cs * 8;
  }
#pragma unroll
  for (int j = 0; j < NBI; ++j) {
    int r = j * 64 + wid * 16 + l4;
    int cs = c4 ^ ((r >> 1) & 3);
    bS[j] = Bbase + (size_t)r * KTOT + cs * 8;
  }

  auto stage = [&](int kt, int buf) {
    u16* as = smem + buf * SLOTU;
    u16* bs = as + 4096;
#pragma unroll
    for (int i = 0; i < 2; ++i)
      async16(aS[i] + kt * 32, as + i * 2048 + wid * 512);
#pragma unroll
    for (int j = 0; j < NBI; ++j)
      async16(bS[j] + kt * 32, bs + j * 2048 + wid * 512);
  };

  f32x4 acc[4][NI] = {};

  stage(0, 0);
  stage(1, 1);
  int bufC = 0, bufS = 2;
#pragma unroll 1
  for (int t = 0; t < NK; ++t) {
    if (t + 1 < NK) {
      if constexpr (LPS == 4) asm volatile("s_waitcnt vmcnt(4)" ::: "memory");
      else                    asm volatile("s_waitcnt vmcnt(3)" ::: "memory");
    } else {
      asm volatile("s_waitcnt vmcnt(0)" ::: "memory");
    }
    __builtin_amdgcn_s_barrier();
    asm volatile("" ::: "memory");
    if (t + 2 < NK) { stage(t + 2, bufS); bufS = (bufS == 2) ? 0 : bufS + 1; }
    const char* AsB = (const char*)(smem + bufC * SLOTU);
    const char* BsB = AsB + 8192;
    int kb = (lane >> 4) << 4;
    bf16x8 av[4], bv[NI];
#pragma unroll
    for (int mi = 0; mi < 4; ++mi) {
      int row = (wm << 6) + (mi << 4) + (lane & 15);
      av[mi] = *(const bf16x8*)(AsB + row * 64 + (kb ^ (((row >> 1) & 3) << 4)));
    }
#pragma unroll
    for (int ni = 0; ni < NI; ++ni) {
      int row = wn * (BN / 2) + (ni << 4) + (lane & 15);
      bv[ni] = *(const bf16x8*)(BsB + row * 64 + (kb ^ (((row >> 1) & 3) << 4)));
    }
    __builtin_amdgcn_s_setprio(1);
#pragma unroll
    for (int mi = 0; mi < 4; ++mi)
#pragma unroll
      for (int ni = 0; ni < NI; ++ni)
        acc[mi][ni] = __builtin_amdgcn_mfma_f32_16x16x32_bf16(av[mi], bv[ni], acc[mi][ni], 0, 0, 0);
    __builtin_amdgcn_s_setprio(0);
    bufC = (bufC == 2) ? 0 : bufC + 1;
  }

  int laneCol = lane & 15;
  int laneRow4 = (lane >> 4) << 2;
  const float* biasE = bias + (size_t)e * NFULL;

  if constexpr (OUTBF16) {
    __syncthreads();
    constexpr int PADW = BN + 8;   // u16 per Cs row (16B-aligned)
    u16* Cs = smem;                // 128 x PADW u16 <= 34KB
#pragma unroll
    for (int mi = 0; mi < 4; ++mi) {
#pragma unroll
      for (int j = 0; j < 4; ++j) {
        int r = (wm << 6) + (mi << 4) + laneRow4 + j;
        int m = posStart + r;
        int mc = m < segEnd ? m : segEnd - 1;
        float w = 1.0f;
        if constexpr (SCALE) w = row_w[mc];
#pragma unroll
        for (int ni = 0; ni < NI; ++ni) {
          int cl = wn * (BN / 2) + (ni << 4) + laneCol;
          float v = acc[mi][ni][j] + (split == 0 ? biasE[nt * BN + cl] : 0.0f);
          if constexpr (GELU) v = gelu_tanh(v);
          if constexpr (SCALE) v *= w;
          Cs[r * PADW + cl] = f2bf(v);
        }
      }
    }
    __syncthreads();
    constexpr int TPR = BN / 8;          // uint4 chunks (= threads) per row
    constexpr int RPP = 256 / TPR;       // rows per pass
    int r0 = tid / TPR, q = tid % TPR;
    u16* OutU = (u16*)Out + (size_t)split * pstride;
#pragma unroll
    for (int i = 0; i < 128 / RPP; ++i) {
      int r = i * RPP + r0;
      if (posStart + r < segEnd)
        *((uint4*)(OutU + (size_t)(posStart + r) * NFULL + nt * BN) + q) =
            ((uint4*)(Cs + (size_t)r * PADW))[q];
    }
  } else {
    float* OutF = (float*)Out + (size_t)split * pstride;
#pragma unroll
    for (int mi = 0; mi < 4; ++mi) {
#pragma unroll
      for (int j = 0; j < 4; ++j) {
        int m = posStart + (wm << 6) + (mi << 4) + laneRow4 + j;
        if (m < segEnd) {
          float w = 1.0f;
          if constexpr (SCALE) w = row_w[m];
#pragma unroll
          for (int ni = 0; ni < NI; ++ni) {
            int n = nt * BN + wn * (BN / 2) + (ni << 4) + laneCol;
            float v = acc[mi][ni][j] + (split == 0 ? biasE[n] : 0.0f);
            OutF[(size_t)m * NFULL + n] = v * w;
          }
        }
      }
    }
  }
}

// ---------- combine: out[tok] = sum over splits x {pos0,pos1} of bf16 partials
template <int NSPLIT>
__global__ void k_combine(const u16* __restrict__ P, size_t pstride,
                          const int* __restrict__ pos_of, float* __restrict__ out, int Ntok) {
  int tok = (blockIdx.x << 2) + (threadIdx.x >> 6);
  int lane = threadIdx.x & 63;
  if (tok >= Ntok) return;
  int p0 = pos_of[tok * 2], p1 = pos_of[tok * 2 + 1];
  float s[8] = {};
#pragma unroll
  for (int sp = 0; sp < NSPLIT; ++sp) {
    bf16x8 a = ((const bf16x8*)(P + sp * pstride + (size_t)p0 * DM))[lane];
    bf16x8 b = ((const bf16x8*)(P + sp * pstride + (size_t)p1 * DM))[lane];
#pragma unroll
    for (int i = 0; i < 8; ++i) s[i] += (float)a[i] + (float)b[i];
  }
  float4* o = (float4*)(out + (size_t)tok * DM + lane * 8);
  o[0] = make_float4(s[0], s[1], s[2], s[3]);
  o[1] = make_float4(s[4], s[5], s[6], s[7]);
}

extern "C" void kernel_launch(void* const* d_in, const int* in_sizes, int n_in,
                              void* d_out, int out_size, void* d_ws, size_t ws_size,
                              hipStream_t stream) {
  const float* x  = (const float*)d_in[0];
  const float* Wr = (const float*)d_in[1];
  const float* br = (const float*)d_in[2];
  const float* W1 = (const float*)d_in[3];
  const float* b1 = (const float*)d_in[4];
  const float* W2 = (const float*)d_in[5];
  const float* b2 = (const float*)d_in[6];
  float* out = (float*)d_out;

  int Ntok = in_sizes[0] / DM;          // 4096
  int npairs = Ntok * 2;                // 8192
  int maxmt = npairs / 128 + NEXP;      // 72
  size_t pstride = (size_t)npairs * DM; // u16 elems per split

  char* p = (char*)d_ws;
  u16* W1T = (u16*)p;  p += (size_t)NEXP * DFF * DM * 2;
  u16* W2T = (u16*)p;  p += (size_t)NEXP * DM * DFF * 2;
  u16* Xb  = (u16*)p;  p += (size_t)Ntok * DM * 2;
  u16* H   = (u16*)p;  p += (size_t)npairs * DFF * 2;
  u16* Part = (u16*)p; p += 2 * pstride * 2;          // [2][npairs][DM] bf16
  int* sel_idx   = (int*)p;   p += (size_t)npairs * 4;
  float* sel_w   = (float*)p; p += (size_t)npairs * 4;
  int* pos_of    = (int*)p;   p += (size_t)npairs * 4;
  int* row_token = (int*)p;   p += (size_t)npairs * 4;
  float* row_w   = (float*)p; p += (size_t)npairs * 4;
  int* tileMeta  = (int*)p;   p += (size_t)(maxmt * 3 + 16) * 4;
  int* gMeta     = (int*)p;   p += 64;

  k_prep<<<dim3(4096 + Ntok / 4), 256, 0, stream>>>(W1, W1T, W2, W2T, x, Xb, Wr, br,
                                                    sel_idx, sel_w, Ntok);
  k_scatter<<<dim3(NEXP), 1024, 0, stream>>>(sel_idx, sel_w, npairs, row_token, row_w,
                                             pos_of, tileMeta, gMeta);
  // GEMM1: BN=64, 36KB LDS -> 4 blocks/CU, grid 72*32 = 2304
  k_gemm<64, DFF, DM, DM, 1, true, false, true, true>
      <<<dim3(maxmt * (DFF / 64)), 256, 0, stream>>>(
          Xb, row_token, W1T, b1, nullptr, H, 0, tileMeta, gMeta, maxmt);
  // GEMM2: BN=64 (occupancy move applied), bf16 partials, split-K=2, grid 72*8*2 = 1152
  k_gemm<64, DM, DFF, DFF / 2, 2, false, true, true, false>
      <<<dim3(maxmt * (DM / 64) * 2), 256, 0, stream>>>(
          H, nullptr, W2T, b2, row_w, Part, pstride, tileMeta, gMeta, maxmt);
  k_combine<2><<<dim3(Ntok / 4), 256, 0, stream>>>(Part, pstride, pos_of, out, Ntok);
}

// Round 18
// 122.255 us; speedup vs baseline: 1.0483x; 1.0483x over previous
//
#include <hip/hip_runtime.h>
#include <hip/hip_bf16.h>
#include <cstdint>

typedef unsigned short u16;
typedef __bf16 bf16_t;
typedef __bf16 bf16x8 __attribute__((ext_vector_type(8)));
typedef float f32x4 __attribute__((ext_vector_type(4)));

#define DM   512
#define DFF  2048
#define NEXP 8

__device__ __forceinline__ u16 f2bf(float f) {
  bf16_t b = (bf16_t)f;
  return __builtin_bit_cast(u16, b);
}
__device__ __forceinline__ uint32_t pack_bf2(float lo, float hi) {
  return (uint32_t)f2bf(lo) | ((uint32_t)f2bf(hi) << 16);
}
__device__ __forceinline__ float gelu_tanh(float x) {
  float x3 = x * x * x;
  float z = 0.7978845608028654f * (x + 0.044715f * x3);
  float az = fabsf(z);
  float e = __expf(2.0f * az);
  float t = 1.0f - 2.0f / (e + 1.0f);
  t = copysignf(t, z);
  return 0.5f * x * (1.0f + t);
}
__device__ __forceinline__ void async16(const u16* g, u16* l) {
  __builtin_amdgcn_global_load_lds((const __attribute__((address_space(1))) void*)g,
                                   (__attribute__((address_space(3))) void*)l, 16, 0, 0);
}

// ---------- transpose tile body: src [R][C] f32 -> dst [C][R] bf16 (16B stores)
__device__ __forceinline__ void transpose_tile(const float* __restrict__ s,
                                               u16* __restrict__ d, int R, int C,
                                               int tileIdx) {
  __shared__ u16 tile[64][66];
  int tilesC = C >> 6;
  int bR = (tileIdx / tilesC) << 6;
  int bC = (tileIdx % tilesC) << 6;
  int rr = threadIdx.x >> 4;
  int cc = (threadIdx.x & 15) << 2;
#pragma unroll
  for (int i = 0; i < 4; ++i) {
    int r = (i << 4) + rr;
    float4 v = *(const float4*)(s + (size_t)(bR + r) * C + bC + cc);
    *(uint32_t*)&tile[r][cc]     = pack_bf2(v.x, v.y);
    *(uint32_t*)&tile[r][cc + 2] = pack_bf2(v.z, v.w);
  }
  __syncthreads();
  int c  = threadIdx.x >> 3;          // 0..31
  int j0 = (threadIdx.x & 7) << 3;    // 0,8,...,56
#pragma unroll
  for (int half = 0; half < 2; ++half) {
    int cc2 = c + (half << 5);
    uint32_t w0 = (uint32_t)tile[j0 + 0][cc2] | ((uint32_t)tile[j0 + 1][cc2] << 16);
    uint32_t w1 = (uint32_t)tile[j0 + 2][cc2] | ((uint32_t)tile[j0 + 3][cc2] << 16);
    uint32_t w2 = (uint32_t)tile[j0 + 4][cc2] | ((uint32_t)tile[j0 + 5][cc2] << 16);
    uint32_t w3 = (uint32_t)tile[j0 + 6][cc2] | ((uint32_t)tile[j0 + 7][cc2] << 16);
    *(uint4*)(&d[(size_t)(bC + cc2) * R + bR + j0]) = make_uint4(w0, w1, w2, w3);
  }
}

// ---------- fused prep: W1 transpose | W2 transpose | router (+x->bf16 folded in)
__global__ void k_prep(const float* __restrict__ W1, u16* __restrict__ W1T,
                       const float* __restrict__ W2, u16* __restrict__ W2T,
                       const float* __restrict__ x, u16* __restrict__ Xb,
                       const float* __restrict__ Wr, const float* __restrict__ br,
                       int* __restrict__ sel_idx, float* __restrict__ sel_w, int Ntok) {
  int b = blockIdx.x;
  if (b < 2048) {
    int e = b >> 8, t = b & 255;
    transpose_tile(W1 + (size_t)e * DM * DFF, W1T + (size_t)e * DM * DFF, DM, DFF, t);
    return;
  }
  if (b < 4096) {
    int e = (b - 2048) >> 8, t = (b - 2048) & 255;
    transpose_tile(W2 + (size_t)e * DFF * DM, W2T + (size_t)e * DFF * DM, DFF, DM, t);
    return;
  }
  int rb = b - 4096;
  int wid = threadIdx.x >> 6;
  int lane = threadIdx.x & 63;
  int tok = (rb << 2) + wid;
  if (tok >= Ntok) return;
  const float4* xr = (const float4*)(x + (size_t)tok * DM);
  float4 x0 = xr[lane * 2], x1 = xr[lane * 2 + 1];
  // fold x->bf16 into router: row already in registers, 16B/lane store
  {
    uint4 o;
    o.x = pack_bf2(x0.x, x0.y);
    o.y = pack_bf2(x0.z, x0.w);
    o.z = pack_bf2(x1.x, x1.y);
    o.w = pack_bf2(x1.z, x1.w);
    ((uint4*)(Xb + (size_t)tok * DM))[lane] = o;
  }
  float logit[NEXP];
#pragma unroll
  for (int e = 0; e < NEXP; ++e) {
    const float4* wr = (const float4*)(Wr + e * DM);
    float4 w0 = wr[lane * 2], w1 = wr[lane * 2 + 1];
    float p = x0.x * w0.x + x0.y * w0.y + x0.z * w0.z + x0.w * w0.w
            + x1.x * w1.x + x1.y * w1.y + x1.z * w1.z + x1.w * w1.w;
#pragma unroll
    for (int off = 32; off; off >>= 1) p += __shfl_xor(p, off, 64);
    logit[e] = p + br[e];
  }
  if (lane == 0) {
    float mx = logit[0];
#pragma unroll
    for (int e = 1; e < NEXP; ++e) mx = fmaxf(mx, logit[e]);
    float pr[NEXP];
#pragma unroll
    for (int e = 0; e < NEXP; ++e) pr[e] = __expf(logit[e] - mx);
    int i0 = 0;
#pragma unroll
    for (int e = 1; e < NEXP; ++e) if (pr[e] > pr[i0]) i0 = e;
    int i1 = -1;
#pragma unroll
    for (int e = 0; e < NEXP; ++e) {
      if (e == i0) continue;
      if (i1 < 0 || pr[e] > pr[i1]) i1 = e;
    }
    float s2 = pr[i0] + pr[i1];
    sel_idx[tok * 2]     = i0;
    sel_idx[tok * 2 + 1] = i1;
    sel_w[tok * 2]       = pr[i0] / s2;
    sel_w[tok * 2 + 1]   = pr[i1] / s2;
  }
}

// ---------- scatter: 8 blocks, one expert each; block 0 also writes tileMeta.
__global__ void k_scatter(const int* __restrict__ sel_idx, const float* __restrict__ sel_w,
                          int npairs, int* __restrict__ row_token, float* __restrict__ row_w,
                          int* __restrict__ pos_of, int* __restrict__ tileMeta,
                          int* __restrict__ gMeta) {
  __shared__ int cnt[NEXP], offs[NEXP], cur;
  int eb = blockIdx.x;
  int tid = threadIdx.x;
  int lane = tid & 63;
  if (tid < NEXP) cnt[tid] = 0;
  if (tid == 0) cur = 0;
  __syncthreads();
  for (int p = tid; p < npairs; p += blockDim.x) {
    int e = sel_idx[p];
#pragma unroll
    for (int ex = 0; ex < NEXP; ++ex) {
      unsigned long long m = __ballot(e == ex);
      if (lane == 0 && m) atomicAdd(&cnt[ex], __popcll(m));
    }
  }
  __syncthreads();
  if (tid == 0) {
    int o = 0;
    for (int e = 0; e < NEXP; ++e) { offs[e] = o; o += cnt[e]; }
    if (eb == 0) {
      int nmt = 0;
      for (int e = 0; e < NEXP; ++e) {
        int c = cnt[e];
        int nt = (c + 127) >> 7;
        for (int t = 0; t < nt; ++t) {
          tileMeta[nmt * 3 + 0] = offs[e] + t * 128;
          tileMeta[nmt * 3 + 1] = offs[e] + c;
          tileMeta[nmt * 3 + 2] = e;
          ++nmt;
        }
      }
      gMeta[0] = nmt;
    }
  }
  __syncthreads();
  for (int p = tid; p < npairs; p += blockDim.x) {
    int e = sel_idx[p];
    unsigned long long m = __ballot(e == eb);
    if (m) {
      int leader = __ffsll((long long)m) - 1;
      int base = 0;
      if (lane == leader) base = atomicAdd(&cur, __popcll(m));
      base = __shfl(base, leader, 64);
      if (e == eb) {
        int pos = offs[eb] + base + __popcll(m & ((1ull << lane) - 1ull));
        row_token[pos] = p >> 1;
        row_w[pos] = sel_w[p];
        pos_of[p] = pos;
      }
    }
  }
}

// ---------- grouped GEMM (R3-proven pipeline), BM=128 x BN (64 or 128), BK=32,
// 3-slot ring, counted vmcnt (one stage in flight), 1 barrier/K-tile,
// 256 thr / 4 waves (2x2). BN=64: slot 12KB -> 36KB LDS -> 4 blocks/CU.
// BN=128: slot 16KB -> 48KB -> 3 blocks/CU.
template <int BN, int NFULL, int KTOT, int KCHUNK, int NSPLIT, bool GELU, bool SCALE,
          bool OUTBF16, bool USEMAP>
__launch_bounds__(256)
__global__ void k_gemm(const u16* __restrict__ A, const int* __restrict__ rowMap,
                       const u16* __restrict__ BT,
                       const float* __restrict__ bias, const float* __restrict__ row_w,
                       void* __restrict__ Out, size_t pstride,
                       const int* __restrict__ tileMeta, const int* __restrict__ gMeta,
                       int maxmt) {
  constexpr int NT  = NFULL / BN;
  constexpr int NK  = KCHUNK / 32;
  constexpr int NI  = BN / 32;              // bv frags per wave (wave covers BN/2 cols)
  constexpr int NBI = BN / 64;              // B staging instrs per tile
  constexpr int SLOTU = (128 + BN) * 32;    // u16 per slot (A 4096 + B BN*32)
  constexpr int LPS = 2 + NBI;              // loads per stage

  __shared__ __align__(16) u16 smem[3 * SLOTU];

  int NB = gridDim.x;
  int bid = blockIdx.x;
  int wg = ((NB & 7) == 0) ? ((bid & 7) * (NB >> 3) + (bid >> 3)) : bid;  // XCD chunking
  int nt = wg % NT;
  int rem = wg / NT;
  int mt = rem % maxmt;
  int split = (NSPLIT == 1) ? 0 : rem / maxmt;
  if (mt >= gMeta[0]) return;
  int posStart = tileMeta[mt * 3 + 0];
  int segEnd   = tileMeta[mt * 3 + 1];
  int e        = tileMeta[mt * 3 + 2];

  int tid = threadIdx.x, lane = tid & 63, wid = tid >> 6;
  int wm = wid >> 1, wn = wid & 1;

  const u16* Abase = A + (size_t)split * KCHUNK;
  const u16* Bbase = BT + ((size_t)e * NFULL + (size_t)nt * BN) * KTOT + (size_t)split * KCHUNK;

  int l4 = lane >> 2, c4 = lane & 3;
  const u16* aS[2];
  const u16* bS[NBI];
#pragma unroll
  for (int i = 0; i < 2; ++i) {
    int r = i * 64 + wid * 16 + l4;
    int gra = posStart + r;
    if (gra >= segEnd) gra = segEnd - 1;
    if constexpr (USEMAP) gra = rowMap[gra];
    int cs = c4 ^ ((r >> 1) & 3);
    aS[i] = Abase + (size_t)gra * KTOT + cs * 8;
  }
#pragma unroll
  for (int j = 0; j < NBI; ++j) {
    int r = j * 64 + wid * 16 + l4;
    int cs = c4 ^ ((r >> 1) & 3);
    bS[j] = Bbase + (size_t)r * KTOT + cs * 8;
  }

  auto stage = [&](int kt, int buf) {
    u16* as = smem + buf * SLOTU;
    u16* bs = as + 4096;
#pragma unroll
    for (int i = 0; i < 2; ++i)
      async16(aS[i] + kt * 32, as + i * 2048 + wid * 512);
#pragma unroll
    for (int j = 0; j < NBI; ++j)
      async16(bS[j] + kt * 32, bs + j * 2048 + wid * 512);
  };

  f32x4 acc[4][NI] = {};

  stage(0, 0);
  stage(1, 1);
  int bufC = 0, bufS = 2;
#pragma unroll 1
  for (int t = 0; t < NK; ++t) {
    if (t + 1 < NK) {
      if constexpr (LPS == 4) asm volatile("s_waitcnt vmcnt(4)" ::: "memory");
      else                    asm volatile("s_waitcnt vmcnt(3)" ::: "memory");
    } else {
      asm volatile("s_waitcnt vmcnt(0)" ::: "memory");
    }
    __builtin_amdgcn_s_barrier();
    asm volatile("" ::: "memory");
    if (t + 2 < NK) { stage(t + 2, bufS); bufS = (bufS == 2) ? 0 : bufS + 1; }
    const char* AsB = (const char*)(smem + bufC * SLOTU);
    const char* BsB = AsB + 8192;
    int kb = (lane >> 4) << 4;
    bf16x8 av[4], bv[NI];
#pragma unroll
    for (int mi = 0; mi < 4; ++mi) {
      int row = (wm << 6) + (mi << 4) + (lane & 15);
      av[mi] = *(const bf16x8*)(AsB + row * 64 + (kb ^ (((row >> 1) & 3) << 4)));
    }
#pragma unroll
    for (int ni = 0; ni < NI; ++ni) {
      int row = wn * (BN / 2) + (ni << 4) + (lane & 15);
      bv[ni] = *(const bf16x8*)(BsB + row * 64 + (kb ^ (((row >> 1) & 3) << 4)));
    }
    __builtin_amdgcn_s_setprio(1);
#pragma unroll
    for (int mi = 0; mi < 4; ++mi)
#pragma unroll
      for (int ni = 0; ni < NI; ++ni)
        acc[mi][ni] = __builtin_amdgcn_mfma_f32_16x16x32_bf16(av[mi], bv[ni], acc[mi][ni], 0, 0, 0);
    __builtin_amdgcn_s_setprio(0);
    bufC = (bufC == 2) ? 0 : bufC + 1;
  }

  int laneCol = lane & 15;
  int laneRow4 = (lane >> 4) << 2;
  const float* biasE = bias + (size_t)e * NFULL;

  if constexpr (OUTBF16) {
    __syncthreads();
    constexpr int PADW = BN + 8;   // u16 per Cs row (16B-aligned)
    u16* Cs = smem;                // 128 x PADW u16 <= 34KB
#pragma unroll
    for (int mi = 0; mi < 4; ++mi) {
#pragma unroll
      for (int j = 0; j < 4; ++j) {
        int r = (wm << 6) + (mi << 4) + laneRow4 + j;
        int m = posStart + r;
        int mc = m < segEnd ? m : segEnd - 1;
        float w = 1.0f;
        if constexpr (SCALE) w = row_w[mc];
#pragma unroll
        for (int ni = 0; ni < NI; ++ni) {
          int cl = wn * (BN / 2) + (ni << 4) + laneCol;
          float v = acc[mi][ni][j] + (split == 0 ? biasE[nt * BN + cl] : 0.0f);
          if constexpr (GELU) v = gelu_tanh(v);
          if constexpr (SCALE) v *= w;
          Cs[r * PADW + cl] = f2bf(v);
        }
      }
    }
    __syncthreads();
    constexpr int TPR = BN / 8;          // uint4 chunks (= threads) per row
    constexpr int RPP = 256 / TPR;       // rows per pass
    int r0 = tid / TPR, q = tid % TPR;
    u16* OutU = (u16*)Out + (size_t)split * pstride;
#pragma unroll
    for (int i = 0; i < 128 / RPP; ++i) {
      int r = i * RPP + r0;
      if (posStart + r < segEnd)
        *((uint4*)(OutU + (size_t)(posStart + r) * NFULL + nt * BN) + q) =
            ((uint4*)(Cs + (size_t)r * PADW))[q];
    }
  } else {
    float* OutF = (float*)Out + (size_t)split * pstride;
#pragma unroll
    for (int mi = 0; mi < 4; ++mi) {
#pragma unroll
      for (int j = 0; j < 4; ++j) {
        int m = posStart + (wm << 6) + (mi << 4) + laneRow4 + j;
        if (m < segEnd) {
          float w = 1.0f;
          if constexpr (SCALE) w = row_w[m];
#pragma unroll
          for (int ni = 0; ni < NI; ++ni) {
            int n = nt * BN + wn * (BN / 2) + (ni << 4) + laneCol;
            float v = acc[mi][ni][j] + (split == 0 ? biasE[n] : 0.0f);
            OutF[(size_t)m * NFULL + n] = v * w;
          }
        }
      }
    }
  }
}

// ---------- combine: out[tok] = sum over splits x {pos0,pos1} of bf16 partials
template <int NSPLIT>
__global__ void k_combine(const u16* __restrict__ P, size_t pstride,
                          const int* __restrict__ pos_of, float* __restrict__ out, int Ntok) {
  int tok = (blockIdx.x << 2) + (threadIdx.x >> 6);
  int lane = threadIdx.x & 63;
  if (tok >= Ntok) return;
  int p0 = pos_of[tok * 2], p1 = pos_of[tok * 2 + 1];
  float s[8] = {};
#pragma unroll
  for (int sp = 0; sp < NSPLIT; ++sp) {
    bf16x8 a = ((const bf16x8*)(P + sp * pstride + (size_t)p0 * DM))[lane];
    bf16x8 b = ((const bf16x8*)(P + sp * pstride + (size_t)p1 * DM))[lane];
#pragma unroll
    for (int i = 0; i < 8; ++i) s[i] += (float)a[i] + (float)b[i];
  }
  float4* o = (float4*)(out + (size_t)tok * DM + lane * 8);
  o[0] = make_float4(s[0], s[1], s[2], s[3]);
  o[1] = make_float4(s[4], s[5], s[6], s[7]);
}

extern "C" void kernel_launch(void* const* d_in, const int* in_sizes, int n_in,
                              void* d_out, int out_size, void* d_ws, size_t ws_size,
                              hipStream_t stream) {
  const float* x  = (const float*)d_in[0];
  const float* Wr = (const float*)d_in[1];
  const float* br = (const float*)d_in[2];
  const float* W1 = (const float*)d_in[3];
  const float* b1 = (const float*)d_in[4];
  const float* W2 = (const float*)d_in[5];
  const float* b2 = (const float*)d_in[6];
  float* out = (float*)d_out;

  int Ntok = in_sizes[0] / DM;          // 4096
  int npairs = Ntok * 2;                // 8192
  int maxmt = npairs / 128 + NEXP;      // 72
  size_t pstride = (size_t)npairs * DM; // u16 elems per split

  char* p = (char*)d_ws;
  u16* W1T = (u16*)p;  p += (size_t)NEXP * DFF * DM * 2;
  u16* W2T = (u16*)p;  p += (size_t)NEXP * DM * DFF * 2;
  u16* Xb  = (u16*)p;  p += (size_t)Ntok * DM * 2;
  u16* H   = (u16*)p;  p += (size_t)npairs * DFF * 2;
  u16* Part = (u16*)p; p += 2 * pstride * 2;          // [2][npairs][DM] bf16
  int* sel_idx   = (int*)p;   p += (size_t)npairs * 4;
  float* sel_w   = (float*)p; p += (size_t)npairs * 4;
  int* pos_of    = (int*)p;   p += (size_t)npairs * 4;
  int* row_token = (int*)p;   p += (size_t)npairs * 4;
  float* row_w   = (float*)p; p += (size_t)npairs * 4;
  int* tileMeta  = (int*)p;   p += (size_t)(maxmt * 3 + 16) * 4;
  int* gMeta     = (int*)p;   p += 64;

  k_prep<<<dim3(4096 + Ntok / 4), 256, 0, stream>>>(W1, W1T, W2, W2T, x, Xb, Wr, br,
                                                    sel_idx, sel_w, Ntok);
  k_scatter<<<dim3(NEXP), 1024, 0, stream>>>(sel_idx, sel_w, npairs, row_token, row_w,
                                             pos_of, tileMeta, gMeta);
  // GEMM1: BN=64, 36KB LDS -> 4 blocks/CU, grid 72*32 = 2304
  k_gemm<64, DFF, DM, DM, 1, true, false, true, true>
      <<<dim3(maxmt * (DFF / 64)), 256, 0, stream>>>(
          Xb, row_token, W1T, b1, nullptr, H, 0, tileMeta, gMeta, maxmt);
  // GEMM2: BN=128 (R16-proven optimum), bf16 partials, split-K=2, grid 72*4*2 = 576
  k_gemm<128, DM, DFF, DFF / 2, 2, false, true, true, false>
      <<<dim3(maxmt * (DM / 128) * 2), 256, 0, stream>>>(
          H, nullptr, W2T, b2, row_w, Part, pstride, tileMeta, gMeta, maxmt);
  k_combine<2><<<dim3(Ntok / 4), 256, 0, stream>>>(Part, pstride, pos_of, out, Ntok);
}